// Round 7
// baseline (469.559 us; speedup 1.0000x reference)
//
#include <hip/hip_runtime.h>
#include <hip/hip_bf16.h>

#define BB 2
#define NN 256
#define HID 256
#define NH 8
#define HD 32
#define NPAIR (BB*NN*NN)   // 131072

typedef __attribute__((ext_vector_type(8))) short bf16x8;
typedef __attribute__((ext_vector_type(4))) float f32x4;

__device__ __forceinline__ unsigned short f2bf(float f){
  union{float f; unsigned int i;} v; v.f=f;
  unsigned int r = v.i + 0x7fffu + ((v.i>>16)&1u);
  return (unsigned short)(r>>16);
}

__device__ __forceinline__ float block_reduce_sum(float v, float* red){
  int t = threadIdx.x;
  red[t]=v; __syncthreads();
  for(int off=128; off>0; off>>=1){ if(t<off) red[t]+=red[t+off]; __syncthreads(); }
  float r = red[0]; __syncthreads();
  return r;
}

// ---------------------------------------------------------------------------
// K0: reordered bf16 weight WcatT[vcol][k] + bias bcat[vcol] (f32).
__global__ void k_build_w(const float* __restrict__ Wep,
                          const float* __restrict__ bep,
                          const float* __restrict__ Weg,
                          const float* __restrict__ beg,
                          unsigned short* __restrict__ WcatT,
                          float* __restrict__ bcat){
  int vcol = blockIdx.x, k = threadIdx.x;
  int hv = vcol >> 6, wi = vcol & 63;
  int col = hv*32 + (wi & 31);
  const float* W = (wi < 32) ? Wep : Weg;
  WcatT[(size_t)vcol*256 + k] = f2bf(W[(size_t)k*256 + col]);
  if (k==0){
    const float* bb = (wi<32) ? bep : beg;
    bcat[vcol] = bb[col];
  }
}

// ---------------------------------------------------------------------------
// K1: fused h = node@Wn+bn ; Q,K,V = h@{Wq,Wk,Wv}+bias.  One block per row.
__global__ __launch_bounds__(256) void k_nodeqkv(
    const float* __restrict__ node, const float* __restrict__ Wn,
    const float* __restrict__ bn,
    const float* __restrict__ Wq, const float* __restrict__ bq,
    const float* __restrict__ Wk, const float* __restrict__ bk,
    const float* __restrict__ Wv, const float* __restrict__ bv,
    float* __restrict__ h,
    float* __restrict__ Q, float* __restrict__ K, float* __restrict__ V){
  __shared__ float xs[128];
  __shared__ float hs[256];
  int row = blockIdx.x, c = threadIdx.x;
  if (c < 128) xs[c] = node[(size_t)row*128 + c];
  __syncthreads();
  float acc = bn[c];
#pragma unroll 16
  for (int k=0;k<128;k++) acc += xs[k]*Wn[(size_t)k*256+c];
  h[(size_t)row*256+c] = acc;
  hs[c] = acc;
  __syncthreads();
  float aq = bq[c], ak = bk[c], av = bv[c];
#pragma unroll 16
  for (int k=0;k<256;k++){
    float x = hs[k];
    aq += x*Wq[(size_t)k*256+c];
    ak += x*Wk[(size_t)k*256+c];
    av += x*Wv[(size_t)k*256+c];
  }
  Q[(size_t)row*256+c]=aq; K[(size_t)row*256+c]=ak; V[(size_t)row*256+c]=av;
}

// ---------------------------------------------------------------------------
// KB: big GEMM. C[131072,512] = edge_f32[131072,256] @ WcatT^T (bf16 MFMA).
// R6: register-prefetch double-buffer. Counters showed latency-bound
// (MfmaUtil 15.9%, VALUBusy 30%, HBM 10%, Occ 30%): the 8 dependent A-loads
// (~500-900cyc) were serialized with compute by the 2-barrier loop. Now
// kc+1's loads issue right after the first barrier, hiding under the MFMA
// phase. Numerics unchanged (same cvt, same MFMA order).
__global__ __launch_bounds__(256) void k_edge_gemm(
    const float* __restrict__ edge,            // [NPAIR][256] fp32
    const unsigned short* __restrict__ WcatT,  // [512][256] bf16
    const float* __restrict__ bcat,            // [512]
    float* __restrict__ edge_attn)             // [B*H][N*N]
{
  __shared__ __align__(16) short As[128][72];
  __shared__ __align__(16) short Bs[128][72];
  int id = blockIdx.x;
  int bm = ((id>>5)<<3) | (id&7);
  int bv = (id>>3)&3;
  int tid = threadIdx.x;
  int w = tid>>6, lane = tid&63;
  int wr = w>>1, wc = w&1;
  int q = lane>>4, cl = lane&15;

  f32x4 acc[4][4];
#pragma unroll
  for(int i=0;i<4;i++)
#pragma unroll
    for(int j=0;j<4;j++) acc[i][j] = (f32x4){0.f,0.f,0.f,0.f};

  int r0 = tid>>4, c4 = tid&15;
  const float* aRow = edge + (size_t)(bm*128 + r0)*256 + c4*4;
  const unsigned short* bRow = WcatT + (size_t)(bv*128 + (tid>>3))*256 + (tid&7)*8;

  float4 fA[8]; uint4 uB[4];
#pragma unroll
  for(int i=0;i<8;i++) fA[i] = *(const float4*)(aRow + (size_t)i*16*256);
#pragma unroll
  for(int i=0;i<4;i++) uB[i] = *(const uint4*)(bRow + (size_t)i*32*256);

  for(int kc=0;kc<4;kc++){
    // write staged regs to LDS (cvt fp32->bf16 packed)
#pragma unroll
    for(int i=0;i<8;i++){
      float4 f = fA[i];
      __hip_bfloat162 lo = __float22bfloat162_rn(make_float2(f.x,f.y));
      __hip_bfloat162 hi = __float22bfloat162_rn(make_float2(f.z,f.w));
      uint2 u; u.x = *(unsigned int*)&lo; u.y = *(unsigned int*)&hi;
      *(uint2*)(&As[r0 + i*16][c4*4]) = u;
    }
#pragma unroll
    for(int i=0;i<4;i++)
      *(uint4*)(&Bs[(tid>>3) + i*32][(tid&7)*8]) = uB[i];
    __syncthreads();
    // issue next tile's loads BEFORE compute: latency hides under MFMAs
    if (kc<3){
      int k1 = (kc+1)*64;
#pragma unroll
      for(int i=0;i<8;i++) fA[i] = *(const float4*)(aRow + (size_t)i*16*256 + k1);
#pragma unroll
      for(int i=0;i<4;i++) uB[i] = *(const uint4*)(bRow + (size_t)i*32*256 + k1);
    }
#pragma unroll
    for(int ks=0;ks<2;ks++){
      int kb = ks*32 + q*8;
      bf16x8 a[4], bfr[4];
#pragma unroll
      for(int tm=0;tm<4;tm++) a[tm]  = *(const bf16x8*)(&As[wr*64+tm*16+cl][kb]);
#pragma unroll
      for(int tn=0;tn<4;tn++) bfr[tn]= *(const bf16x8*)(&Bs[wc*64+tn*16+cl][kb]);
#pragma unroll
      for(int tm=0;tm<4;tm++)
#pragma unroll
        for(int tn=0;tn<4;tn++)
          acc[tm][tn] = __builtin_amdgcn_mfma_f32_16x16x32_bf16(a[tm], bfr[tn], acc[tm][tn], 0, 0, 0);
    }
    __syncthreads();
  }

  // epilogue: gated reduce over head_dim. tn 0,1 = eh cols, tn 2,3 = eg cols.
  int head = bv*2 + wc;
  float bias[4];
#pragma unroll
  for(int tn=0;tn<4;tn++) bias[tn] = bcat[bv*128 + wc*64 + tn*16 + cl];

#pragma unroll
  for(int tm=0;tm<4;tm++){
    float s[4] = {0.f,0.f,0.f,0.f};
#pragma unroll
    for(int tn=0;tn<2;tn++){
#pragma unroll
      for(int r=0;r<4;r++){
        float eh = acc[tm][tn][r]   + bias[tn];
        float gg = acc[tm][tn+2][r] + bias[tn+2];
        s[r] += eh * (1.f/(1.f + __expf(-gg)));
      }
    }
#pragma unroll
    for(int off=1;off<16;off<<=1){
#pragma unroll
      for(int r=0;r<4;r++) s[r] += __shfl_xor(s[r], off);
    }
    if (cl==0){
      int R = bm*128 + wr*64 + tm*16 + q*4;
      int b = R>>16, rem = R&65535;
#pragma unroll
      for(int r=0;r<4;r++)
        edge_attn[(size_t)(b*NH+head)*65536 + rem + r] = s[r];
    }
  }
}

// ---------------------------------------------------------------------------
// KC: barrier-light attention. Block = (b, hh, 4 query rows); one wave per row.
__global__ __launch_bounds__(256) void k_attn(
    const float* __restrict__ Q, const float* __restrict__ Km,
    const float* __restrict__ V, const int* __restrict__ adj,
    float* __restrict__ attn, float* __restrict__ attn_out){
  __shared__ float Ks[256][33];
  __shared__ float Vs[256][33];
  __shared__ float arow[4][264];
  int b = blockIdx.z, hh = blockIdx.y;
  int t = threadIdx.x;
  int mrow = t>>3, dg = (t&7)*4;
#pragma unroll
  for(int it=0; it<8; it++){
    int m = mrow + it*32;
    size_t base = ((size_t)(b*NN+m))*HID + hh*HD + dg;
    *(float4*)&Ks[m][dg] = *(const float4*)(Km + base);
    *(float4*)&Vs[m][dg] = *(const float4*)(V + base);
  }
  __syncthreads();

  int w = t>>6, lane = t&63;
  int n = blockIdx.x*4 + w;
  const float* qp = Q + ((size_t)(b*NN+n))*HID + hh*HD;
  float4 q[8];
#pragma unroll
  for(int i=0;i<8;i++) q[i] = *(const float4*)(qp + i*4);

  size_t eoff = ((size_t)((b*NH+hh)*NN + n))*NN;
  const int* abase = adj + ((size_t)(b*NN+n))*NN;
  float sc[4];
#pragma unroll
  for(int j=0;j<4;j++){
    int m = lane + j*64;
    float d = 0.f;
#pragma unroll
    for(int i=0;i<8;i++){
      float4 kk = *(float4*)&Ks[m][i*4];
      d += q[i].x*kk.x + q[i].y*kk.y + q[i].z*kk.z + q[i].w*kk.w;
    }
    float s = d*0.17677669529663687f + attn[eoff + m];
    if (abase[m]==0) s = -1e9f;
    sc[j] = s;
  }
  float mx = fmaxf(fmaxf(sc[0],sc[1]),fmaxf(sc[2],sc[3]));
#pragma unroll
  for(int off=1;off<64;off<<=1) mx = fmaxf(mx, __shfl_xor(mx, off));
  float e[4], sum = 0.f;
#pragma unroll
  for(int j=0;j<4;j++){ e[j] = __expf(sc[j]-mx); sum += e[j]; }
#pragma unroll
  for(int off=1;off<64;off<<=1) sum += __shfl_xor(sum, off);
  float inv = 1.f/sum;
#pragma unroll
  for(int j=0;j<4;j++){
    int m = lane + j*64;
    float a = e[j]*inv;
    attn[eoff + m] = a;
    arow[w][m + (m>>5)] = a;   // stride-33 chunks: AV broadcast reads conflict-free
  }
  // AV: lane = mc*32-chunk x 4-d-group. o[dg4..dg4+3] = sum_m a[m]*V[m][dg4..]
  int mc = lane>>3, dg4 = (lane&7)*4;
  float4 o = {0.f,0.f,0.f,0.f};
#pragma unroll
  for(int j=0;j<32;j++){
    int m = mc*32 + j;
    float a = arow[w][m + (m>>5)];
    float4 v = *(float4*)&Vs[m][dg4];
    o.x += a*v.x; o.y += a*v.y; o.z += a*v.z; o.w += a*v.w;
  }
#pragma unroll
  for(int off=8; off<64; off<<=1){
    o.x += __shfl_xor(o.x, off); o.y += __shfl_xor(o.y, off);
    o.z += __shfl_xor(o.z, off); o.w += __shfl_xor(o.w, off);
  }
  if (mc==0)
    *(float4*)(attn_out + ((size_t)(b*NN+n))*HID + hh*HD + dg4) = o;
}

// ---------------------------------------------------------------------------
// KD: fused h_out = LN(h + attn_out@Wo + bo) -> d_out ; P = h_out@Weo
__global__ __launch_bounds__(256) void k_hout(
    const float* __restrict__ attn_out, const float* __restrict__ hres,
    const float* __restrict__ Wo, const float* __restrict__ bo,
    const float* __restrict__ g1, const float* __restrict__ b1,
    const float* __restrict__ Weo,
    float* __restrict__ P, float* __restrict__ out){
  __shared__ float xs[256]; __shared__ float red[256]; __shared__ float hs[256];
  int row = blockIdx.x, c = threadIdx.x;
  xs[c] = attn_out[(size_t)row*256 + c];
  __syncthreads();
  float acc = bo[c];
#pragma unroll 16
  for(int k=0;k<256;k++) acc += xs[k]*Wo[(size_t)k*256+c];
  float val = hres[(size_t)row*256+c] + acc;
  float mean = block_reduce_sum(val, red) * (1.f/256.f);
  float ctr = val - mean;
  float var = block_reduce_sum(ctr*ctr, red) * (1.f/256.f);
  float o = ctr * rsqrtf(var + 1e-5f) * g1[c] + b1[c];
  out[(size_t)row*256+c] = o;
  hs[c] = o;
  __syncthreads();
  float accP = 0.f;
#pragma unroll 16
  for(int k=0;k<256;k++) accP += hs[k]*Weo[(size_t)k*256+c];
  P[(size_t)row*256+c] = accP;
}

// ---------------------------------------------------------------------------
// KE: edge_out = LN(edge + attn_mean*0.5*(P[n]+P[m]) + beo). One wave per pair.
// R6: k_attn_mean folded in — wave sums the 8 head probs directly (broadcast
// same-address loads). 0.125*0.5 = 0.0625 exact pow2 -> bitwise identical.
__global__ __launch_bounds__(256) void k_edge_out(
    const float* __restrict__ ef, const float* __restrict__ attn,
    const float* __restrict__ P, const float* __restrict__ beo,
    const float* __restrict__ g2, const float* __restrict__ b2,
    float* __restrict__ out){
  int w = threadIdx.x>>6, lane = threadIdx.x&63;
  size_t pair = (size_t)blockIdx.x*4 + w;
  int b = (int)(pair>>16); int rem = (int)(pair&65535);
  int n = rem>>8, m = rem&255;
  const float* ap = attn + (size_t)b*NH*65536 + rem;
  float ssum = 0.f;
#pragma unroll
  for(int hh=0; hh<NH; hh++) ssum += ap[(size_t)hh*65536];
  float a = ssum * 0.0625f;   // mean/8 then *0.5
  const float* Pn = P + (size_t)(b*NN+n)*HID;
  const float* Pm = P + (size_t)(b*NN+m)*HID;
  int c0 = lane*4;
  float4 ev = *(const float4*)(ef + pair*256 + c0);
  float4 pn = *(const float4*)(Pn + c0);
  float4 pm = *(const float4*)(Pm + c0);
  float4 bo4 = *(const float4*)(beo + c0);
  float v0 = ev.x + a*(pn.x+pm.x) + bo4.x;
  float v1 = ev.y + a*(pn.y+pm.y) + bo4.y;
  float v2 = ev.z + a*(pn.z+pm.z) + bo4.z;
  float v3 = ev.w + a*(pn.w+pm.w) + bo4.w;
  float s = v0+v1+v2+v3;
#pragma unroll
  for(int off=1;off<64;off<<=1) s += __shfl_xor(s, off);
  float mean = s*(1.f/256.f);
  float c0f=v0-mean, c1f=v1-mean, c2f=v2-mean, c3f=v3-mean;
  float sq = c0f*c0f+c1f*c1f+c2f*c2f+c3f*c3f;
#pragma unroll
  for(int off=1;off<64;off<<=1) sq += __shfl_xor(sq, off);
  float rs = rsqrtf(sq*(1.f/256.f) + 1e-5f);
  float4 g = *(const float4*)(g2 + c0);
  float4 bb = *(const float4*)(b2 + c0);
  float4 o;
  o.x = c0f*rs*g.x+bb.x;
  o.y = c1f*rs*g.y+bb.y;
  o.z = c2f*rs*g.z+bb.z;
  o.w = c3f*rs*g.w+bb.w;
  *(float4*)(out + pair*256 + c0) = o;
}

// ---------------------------------------------------------------------------
extern "C" void kernel_launch(void* const* d_in, const int* in_sizes, int n_in,
                              void* d_out, int out_size, void* d_ws, size_t ws_size,
                              hipStream_t stream){
  (void)in_sizes; (void)n_in; (void)out_size; (void)ws_size;
  const float* node = (const float*)d_in[0];
  const float* edge = (const float*)d_in[1];
  const int*   adj  = (const int*)d_in[2];
  const float* Wn  = (const float*)d_in[3];
  const float* bn  = (const float*)d_in[4];
  const float* Wq  = (const float*)d_in[5];
  const float* bq  = (const float*)d_in[6];
  const float* Wk  = (const float*)d_in[7];
  const float* bk  = (const float*)d_in[8];
  const float* Wv  = (const float*)d_in[9];
  const float* bv  = (const float*)d_in[10];
  const float* Wep = (const float*)d_in[11];
  const float* bep = (const float*)d_in[12];
  const float* Weg = (const float*)d_in[13];
  const float* beg = (const float*)d_in[14];
  const float* Wo  = (const float*)d_in[15];
  const float* bo  = (const float*)d_in[16];
  const float* Weo = (const float*)d_in[17];
  const float* beo = (const float*)d_in[18];
  const float* g1  = (const float*)d_in[19];
  const float* b1  = (const float*)d_in[20];
  const float* g2  = (const float*)d_in[21];
  const float* b2  = (const float*)d_in[22];

  unsigned short* WcatT = (unsigned short*)d_ws;               // 512*256 bf16
  float* fws  = (float*)((char*)d_ws + (size_t)512*256*2);
  float* bcat = fws;                 // 512
  float* h    = bcat + 512;          // 131072
  float* Q    = h    + 131072;
  float* K    = Q    + 131072;
  float* V    = K    + 131072;
  float* attn = V    + 131072;       // 1048576 (edge_attn, then attn in place)
  float* am   = attn + 1048576;      // 131072 (unused since R6; layout kept)
  float* P    = am   + 131072;       // 131072
  float* aout = P    + 131072;       // 131072

  float* out = (float*)d_out;

  k_build_w  <<<512, 256, 0, stream>>>(Wep, bep, Weg, beg, WcatT, bcat);
  k_nodeqkv  <<<512, 256, 0, stream>>>(node, Wn, bn, Wq, bq, Wk, bk, Wv, bv, h, Q, K, V);
  k_edge_gemm<<<4096, 256, 0, stream>>>(edge, WcatT, bcat, attn);
  k_attn     <<<dim3(64,8,2), 256, 0, stream>>>(Q, K, V, adj, attn, aout);
  k_hout     <<<512, 256, 0, stream>>>(aout, h, Wo, bo, g1, b1, Weo, P, out);
  k_edge_out <<<32768, 256, 0, stream>>>(edge, attn, P, beo, g2, b2, out + (size_t)BB*NN*HID);
}

// Round 8
// 455.367 us; speedup vs baseline: 1.0312x; 1.0312x over previous
//
#include <hip/hip_runtime.h>
#include <hip/hip_bf16.h>

#define BB 2
#define NN 256
#define HID 256
#define NH 8
#define HD 32
#define NPAIR (BB*NN*NN)   // 131072

typedef __attribute__((ext_vector_type(8))) short bf16x8;
typedef __attribute__((ext_vector_type(4))) float f32x4;

__device__ __forceinline__ unsigned short f2bf(float f){
  union{float f; unsigned int i;} v; v.f=f;
  unsigned int r = v.i + 0x7fffu + ((v.i>>16)&1u);
  return (unsigned short)(r>>16);
}

__device__ __forceinline__ float block_reduce_sum(float v, float* red){
  int t = threadIdx.x;
  red[t]=v; __syncthreads();
  for(int off=128; off>0; off>>=1){ if(t<off) red[t]+=red[t+off]; __syncthreads(); }
  float r = red[0]; __syncthreads();
  return r;
}

// ---------------------------------------------------------------------------
// K0: reordered bf16 weight WcatT[vcol][k] + bias bcat[vcol] (f32).
__global__ void k_build_w(const float* __restrict__ Wep,
                          const float* __restrict__ bep,
                          const float* __restrict__ Weg,
                          const float* __restrict__ beg,
                          unsigned short* __restrict__ WcatT,
                          float* __restrict__ bcat){
  int vcol = blockIdx.x, k = threadIdx.x;
  int hv = vcol >> 6, wi = vcol & 63;
  int col = hv*32 + (wi & 31);
  const float* W = (wi < 32) ? Wep : Weg;
  WcatT[(size_t)vcol*256 + k] = f2bf(W[(size_t)k*256 + col]);
  if (k==0){
    const float* bb = (wi<32) ? bep : beg;
    bcat[vcol] = bb[col];
  }
}

// ---------------------------------------------------------------------------
// K1: fused h = node@Wn+bn ; Q,K,V = h@{Wq,Wk,Wv}+bias.  One block per row.
__global__ __launch_bounds__(256) void k_nodeqkv(
    const float* __restrict__ node, const float* __restrict__ Wn,
    const float* __restrict__ bn,
    const float* __restrict__ Wq, const float* __restrict__ bq,
    const float* __restrict__ Wk, const float* __restrict__ bk,
    const float* __restrict__ Wv, const float* __restrict__ bv,
    float* __restrict__ h,
    float* __restrict__ Q, float* __restrict__ K, float* __restrict__ V){
  __shared__ float xs[128];
  __shared__ float hs[256];
  int row = blockIdx.x, c = threadIdx.x;
  if (c < 128) xs[c] = node[(size_t)row*128 + c];
  __syncthreads();
  float acc = bn[c];
#pragma unroll 16
  for (int k=0;k<128;k++) acc += xs[k]*Wn[(size_t)k*256+c];
  h[(size_t)row*256+c] = acc;
  hs[c] = acc;
  __syncthreads();
  float aq = bq[c], ak = bk[c], av = bv[c];
#pragma unroll 16
  for (int k=0;k<256;k++){
    float x = hs[k];
    aq += x*Wq[(size_t)k*256+c];
    ak += x*Wk[(size_t)k*256+c];
    av += x*Wv[(size_t)k*256+c];
  }
  Q[(size_t)row*256+c]=aq; K[(size_t)row*256+c]=ak; V[(size_t)row*256+c]=av;
}

// ---------------------------------------------------------------------------
// KB: big GEMM. C[131072,512] = edge_f32[131072,256] @ WcatT^T (bf16 MFMA).
// R7 redesign from counters (R6: 88.5µs latency-bound, MfmaUtil 16%;
// R7 reg-prefetch spilled: WRITE_SIZE 4->52MB, 160µs):
//  - BK=32, double-buffered A LDS (As[2][128][40], 40KB) -> ONE barrier/step,
//    waves+blocks de-phase instead of stalling together.
//  - B read per-fragment directly from global (WcatT 256KB = L2-resident);
//    no Bs LDS, no B staging.
//  - T14 split: A-loads issue BEFORE MFMAs, cvt+LDS-write AFTER (only 16
//    transient VGPRs across MFMA; launch_bounds(256,4) caps at 128 -> no spill).
//  - k-step order 0..7 identical to R6 -> bitwise-identical accumulation.
__global__ __launch_bounds__(256, 4) void k_edge_gemm(
    const float* __restrict__ edge,            // [NPAIR][256] fp32
    const unsigned short* __restrict__ WcatT,  // [512][256] bf16
    const float* __restrict__ bcat,            // [512]
    float* __restrict__ edge_attn)             // [B*H][N*N]
{
  __shared__ __align__(16) short As[2][128][40];   // 40-short stride: 16B-aligned rows, 2-way banks
  int id = blockIdx.x;
  int bm = ((id>>5)<<3) | (id&7);
  int bv = (id>>3)&3;
  int tid = threadIdx.x;
  int w = tid>>6, lane = tid&63;
  int wr = w>>1, wc = w&1;
  int q = lane>>4, cl = lane&15;

  f32x4 acc[4][4];
#pragma unroll
  for(int i=0;i<4;i++)
#pragma unroll
    for(int j=0;j<4;j++) acc[i][j] = (f32x4){0.f,0.f,0.f,0.f};

  // A staging map: thread -> rows r0,r0+32,r0+64,r0+96 at float4-group grp
  int r0 = tid>>3, grp4 = (tid&7)*4;
  const float* aP = edge + (size_t)(bm*128 + r0)*256 + grp4;

  // prologue: stage k-step 0 into buf 0
  {
    float4 f0 = *(const float4*)(aP);
    float4 f1 = *(const float4*)(aP + 32*256);
    float4 f2 = *(const float4*)(aP + 64*256);
    float4 f3 = *(const float4*)(aP + 96*256);
#define CVT_WR(BUF,ROW,F) { \
    __hip_bfloat162 lo_ = __float22bfloat162_rn(make_float2((F).x,(F).y)); \
    __hip_bfloat162 hi_ = __float22bfloat162_rn(make_float2((F).z,(F).w)); \
    uint2 u_; u_.x = *(unsigned int*)&lo_; u_.y = *(unsigned int*)&hi_; \
    *(uint2*)(&As[BUF][ROW][grp4]) = u_; }
    CVT_WR(0, r0,      f0);
    CVT_WR(0, r0+32,   f1);
    CVT_WR(0, r0+64,   f2);
    CVT_WR(0, r0+96,   f3);
  }
  __syncthreads();

  const unsigned short* bP = WcatT + (size_t)(bv*128 + wc*64 + cl)*256 + q*8;

  for (int kt=0; kt<8; ++kt){
    int cur = kt&1;
    bool pf = (kt < 7);
    float4 f0,f1,f2,f3;
    if (pf){                         // issue next step's A loads EARLY
      int k1 = (kt+1)*32;
      f0 = *(const float4*)(aP + k1);
      f1 = *(const float4*)(aP + 32*256 + k1);
      f2 = *(const float4*)(aP + 64*256 + k1);
      f3 = *(const float4*)(aP + 96*256 + k1);
    }
    bf16x8 bfr[4], a[4];
#pragma unroll
    for(int tn=0;tn<4;tn++)
      bfr[tn] = *(const bf16x8*)(bP + (size_t)tn*4096 + kt*32);   // L2-hit B frags
#pragma unroll
    for(int tm=0;tm<4;tm++)
      a[tm] = *(const bf16x8*)(&As[cur][wr*64 + tm*16 + cl][q*8]);
#pragma unroll
    for(int tm=0;tm<4;tm++)
#pragma unroll
      for(int tn=0;tn<4;tn++)
        acc[tm][tn] = __builtin_amdgcn_mfma_f32_16x16x32_bf16(a[tm], bfr[tn], acc[tm][tn], 0, 0, 0);
    if (pf){                         // cvt+write LATE (loads had MFMA phase to land)
      int nb = cur^1;
      CVT_WR(nb, r0,      f0);
      CVT_WR(nb, r0+32,   f1);
      CVT_WR(nb, r0+64,   f2);
      CVT_WR(nb, r0+96,   f3);
    }
    __syncthreads();
  }
#undef CVT_WR

  // epilogue: gated reduce over head_dim. tn 0,1 = eh cols, tn 2,3 = eg cols.
  int head = bv*2 + wc;
  float bias[4];
#pragma unroll
  for(int tn=0;tn<4;tn++) bias[tn] = bcat[bv*128 + wc*64 + tn*16 + cl];

#pragma unroll
  for(int tm=0;tm<4;tm++){
    float s[4] = {0.f,0.f,0.f,0.f};
#pragma unroll
    for(int tn=0;tn<2;tn++){
#pragma unroll
      for(int r=0;r<4;r++){
        float eh = acc[tm][tn][r]   + bias[tn];
        float gg = acc[tm][tn+2][r] + bias[tn+2];
        s[r] += eh * (1.f/(1.f + __expf(-gg)));
      }
    }
#pragma unroll
    for(int off=1;off<16;off<<=1){
#pragma unroll
      for(int r=0;r<4;r++) s[r] += __shfl_xor(s[r], off);
    }
    if (cl==0){
      int R = bm*128 + wr*64 + tm*16 + q*4;
      int b = R>>16, rem = R&65535;
#pragma unroll
      for(int r=0;r<4;r++)
        edge_attn[(size_t)(b*NH+head)*65536 + rem + r] = s[r];
    }
  }
}

// ---------------------------------------------------------------------------
// KC: barrier-light attention. Block = (b, hh, 4 query rows); one wave per row.
__global__ __launch_bounds__(256) void k_attn(
    const float* __restrict__ Q, const float* __restrict__ Km,
    const float* __restrict__ V, const int* __restrict__ adj,
    float* __restrict__ attn, float* __restrict__ attn_out){
  __shared__ float Ks[256][33];
  __shared__ float Vs[256][33];
  __shared__ float arow[4][264];
  int b = blockIdx.z, hh = blockIdx.y;
  int t = threadIdx.x;
  int mrow = t>>3, dg = (t&7)*4;
#pragma unroll
  for(int it=0; it<8; it++){
    int m = mrow + it*32;
    size_t base = ((size_t)(b*NN+m))*HID + hh*HD + dg;
    *(float4*)&Ks[m][dg] = *(const float4*)(Km + base);
    *(float4*)&Vs[m][dg] = *(const float4*)(V + base);
  }
  __syncthreads();

  int w = t>>6, lane = t&63;
  int n = blockIdx.x*4 + w;
  const float* qp = Q + ((size_t)(b*NN+n))*HID + hh*HD;
  float4 q[8];
#pragma unroll
  for(int i=0;i<8;i++) q[i] = *(const float4*)(qp + i*4);

  size_t eoff = ((size_t)((b*NH+hh)*NN + n))*NN;
  const int* abase = adj + ((size_t)(b*NN+n))*NN;
  float sc[4];
#pragma unroll
  for(int j=0;j<4;j++){
    int m = lane + j*64;
    float d = 0.f;
#pragma unroll
    for(int i=0;i<8;i++){
      float4 kk = *(float4*)&Ks[m][i*4];
      d += q[i].x*kk.x + q[i].y*kk.y + q[i].z*kk.z + q[i].w*kk.w;
    }
    float s = d*0.17677669529663687f + attn[eoff + m];
    if (abase[m]==0) s = -1e9f;
    sc[j] = s;
  }
  float mx = fmaxf(fmaxf(sc[0],sc[1]),fmaxf(sc[2],sc[3]));
#pragma unroll
  for(int off=1;off<64;off<<=1) mx = fmaxf(mx, __shfl_xor(mx, off));
  float e[4], sum = 0.f;
#pragma unroll
  for(int j=0;j<4;j++){ e[j] = __expf(sc[j]-mx); sum += e[j]; }
#pragma unroll
  for(int off=1;off<64;off<<=1) sum += __shfl_xor(sum, off);
  float inv = 1.f/sum;
#pragma unroll
  for(int j=0;j<4;j++){
    int m = lane + j*64;
    float a = e[j]*inv;
    attn[eoff + m] = a;
    arow[w][m + (m>>5)] = a;   // stride-33 chunks: AV broadcast reads conflict-free
  }
  // AV: lane = mc*32-chunk x 4-d-group. o[dg4..dg4+3] = sum_m a[m]*V[m][dg4..]
  int mc = lane>>3, dg4 = (lane&7)*4;
  float4 o = {0.f,0.f,0.f,0.f};
#pragma unroll
  for(int j=0;j<32;j++){
    int m = mc*32 + j;
    float a = arow[w][m + (m>>5)];
    float4 v = *(float4*)&Vs[m][dg4];
    o.x += a*v.x; o.y += a*v.y; o.z += a*v.z; o.w += a*v.w;
  }
#pragma unroll
  for(int off=8; off<64; off<<=1){
    o.x += __shfl_xor(o.x, off); o.y += __shfl_xor(o.y, off);
    o.z += __shfl_xor(o.z, off); o.w += __shfl_xor(o.w, off);
  }
  if (mc==0)
    *(float4*)(attn_out + ((size_t)(b*NN+n))*HID + hh*HD + dg4) = o;
}

// ---------------------------------------------------------------------------
// KC3: attn_mean = mean over heads (R7: restored — R6 fusion measured +6.5µs)
__global__ void k_attn_mean(const float* __restrict__ attn, float* __restrict__ am){
  int p = blockIdx.x*256 + threadIdx.x;
  int b = p>>16, rem = p&65535;
  float s = 0.f;
#pragma unroll
  for(int hh=0; hh<NH; hh++) s += attn[(size_t)(b*NH+hh)*65536 + rem];
  am[p] = s*0.125f;
}

// ---------------------------------------------------------------------------
// KD: fused h_out = LN(h + attn_out@Wo + bo) -> d_out ; P = h_out@Weo
__global__ __launch_bounds__(256) void k_hout(
    const float* __restrict__ attn_out, const float* __restrict__ hres,
    const float* __restrict__ Wo, const float* __restrict__ bo,
    const float* __restrict__ g1, const float* __restrict__ b1,
    const float* __restrict__ Weo,
    float* __restrict__ P, float* __restrict__ out){
  __shared__ float xs[256]; __shared__ float red[256]; __shared__ float hs[256];
  int row = blockIdx.x, c = threadIdx.x;
  xs[c] = attn_out[(size_t)row*256 + c];
  __syncthreads();
  float acc = bo[c];
#pragma unroll 16
  for(int k=0;k<256;k++) acc += xs[k]*Wo[(size_t)k*256+c];
  float val = hres[(size_t)row*256+c] + acc;
  float mean = block_reduce_sum(val, red) * (1.f/256.f);
  float ctr = val - mean;
  float var = block_reduce_sum(ctr*ctr, red) * (1.f/256.f);
  float o = ctr * rsqrtf(var + 1e-5f) * g1[c] + b1[c];
  out[(size_t)row*256+c] = o;
  hs[c] = o;
  __syncthreads();
  float accP = 0.f;
#pragma unroll 16
  for(int k=0;k<256;k++) accP += hs[k]*Weo[(size_t)k*256+c];
  P[(size_t)row*256+c] = accP;
}

// ---------------------------------------------------------------------------
// KE: edge_out = LN(edge + attn_mean*0.5*(P[n]+P[m]) + beo). One wave per pair.
__global__ __launch_bounds__(256) void k_edge_out(
    const float* __restrict__ ef, const float* __restrict__ am,
    const float* __restrict__ P, const float* __restrict__ beo,
    const float* __restrict__ g2, const float* __restrict__ b2,
    float* __restrict__ out){
  int w = threadIdx.x>>6, lane = threadIdx.x&63;
  size_t pair = (size_t)blockIdx.x*4 + w;
  int b = (int)(pair>>16); int rem = (int)(pair&65535);
  int n = rem>>8, m = rem&255;
  float a = am[pair]*0.5f;
  const float* Pn = P + (size_t)(b*NN+n)*HID;
  const float* Pm = P + (size_t)(b*NN+m)*HID;
  int c0 = lane*4;
  float4 ev = *(const float4*)(ef + pair*256 + c0);
  float4 pn = *(const float4*)(Pn + c0);
  float4 pm = *(const float4*)(Pm + c0);
  float4 bo4 = *(const float4*)(beo + c0);
  float v0 = ev.x + a*(pn.x+pm.x) + bo4.x;
  float v1 = ev.y + a*(pn.y+pm.y) + bo4.y;
  float v2 = ev.z + a*(pn.z+pm.z) + bo4.z;
  float v3 = ev.w + a*(pn.w+pm.w) + bo4.w;
  float s = v0+v1+v2+v3;
#pragma unroll
  for(int off=1;off<64;off<<=1) s += __shfl_xor(s, off);
  float mean = s*(1.f/256.f);
  float c0f=v0-mean, c1f=v1-mean, c2f=v2-mean, c3f=v3-mean;
  float sq = c0f*c0f+c1f*c1f+c2f*c2f+c3f*c3f;
#pragma unroll
  for(int off=1;off<64;off<<=1) sq += __shfl_xor(sq, off);
  float rs = rsqrtf(sq*(1.f/256.f) + 1e-5f);
  float4 g = *(const float4*)(g2 + c0);
  float4 bb = *(const float4*)(b2 + c0);
  float4 o;
  o.x = c0f*rs*g.x+bb.x;
  o.y = c1f*rs*g.y+bb.y;
  o.z = c2f*rs*g.z+bb.z;
  o.w = c3f*rs*g.w+bb.w;
  *(float4*)(out + pair*256 + c0) = o;
}

// ---------------------------------------------------------------------------
extern "C" void kernel_launch(void* const* d_in, const int* in_sizes, int n_in,
                              void* d_out, int out_size, void* d_ws, size_t ws_size,
                              hipStream_t stream){
  (void)in_sizes; (void)n_in; (void)out_size; (void)ws_size;
  const float* node = (const float*)d_in[0];
  const float* edge = (const float*)d_in[1];
  const int*   adj  = (const int*)d_in[2];
  const float* Wn  = (const float*)d_in[3];
  const float* bn  = (const float*)d_in[4];
  const float* Wq  = (const float*)d_in[5];
  const float* bq  = (const float*)d_in[6];
  const float* Wk  = (const float*)d_in[7];
  const float* bk  = (const float*)d_in[8];
  const float* Wv  = (const float*)d_in[9];
  const float* bv  = (const float*)d_in[10];
  const float* Wep = (const float*)d_in[11];
  const float* bep = (const float*)d_in[12];
  const float* Weg = (const float*)d_in[13];
  const float* beg = (const float*)d_in[14];
  const float* Wo  = (const float*)d_in[15];
  const float* bo  = (const float*)d_in[16];
  const float* Weo = (const float*)d_in[17];
  const float* beo = (const float*)d_in[18];
  const float* g1  = (const float*)d_in[19];
  const float* b1  = (const float*)d_in[20];
  const float* g2  = (const float*)d_in[21];
  const float* b2  = (const float*)d_in[22];

  unsigned short* WcatT = (unsigned short*)d_ws;               // 512*256 bf16
  float* fws  = (float*)((char*)d_ws + (size_t)512*256*2);
  float* bcat = fws;                 // 512
  float* h    = bcat + 512;          // 131072
  float* Q    = h    + 131072;
  float* K    = Q    + 131072;
  float* V    = K    + 131072;
  float* attn = V    + 131072;       // 1048576 (edge_attn, then attn in place)
  float* am   = attn + 1048576;      // 131072
  float* P    = am   + 131072;       // 131072
  float* aout = P    + 131072;       // 131072

  float* out = (float*)d_out;

  k_build_w  <<<512, 256, 0, stream>>>(Wep, bep, Weg, beg, WcatT, bcat);
  k_nodeqkv  <<<512, 256, 0, stream>>>(node, Wn, bn, Wq, bq, Wk, bk, Wv, bv, h, Q, K, V);
  k_edge_gemm<<<4096, 256, 0, stream>>>(edge, WcatT, bcat, attn);
  k_attn     <<<dim3(64,8,2), 256, 0, stream>>>(Q, K, V, adj, attn, aout);
  k_attn_mean<<<512, 256, 0, stream>>>(attn, am);
  k_hout     <<<512, 256, 0, stream>>>(aout, h, Wo, bo, g1, b1, Weo, P, out);
  k_edge_out <<<32768, 256, 0, stream>>>(edge, am, P, beo, g2, b2, out + (size_t)BB*NN*HID);
}

// Round 9
// 423.571 us; speedup vs baseline: 1.1086x; 1.0751x over previous
//
#include <hip/hip_runtime.h>
#include <hip/hip_bf16.h>

#define BB 2
#define NN 256
#define HID 256
#define NH 8
#define HD 32
#define NPAIR (BB*NN*NN)   // 131072

typedef __attribute__((ext_vector_type(8))) short bf16x8;
typedef __attribute__((ext_vector_type(4))) float f32x4;

__device__ __forceinline__ unsigned short f2bf(float f){
  union{float f; unsigned int i;} v; v.f=f;
  unsigned int r = v.i + 0x7fffu + ((v.i>>16)&1u);
  return (unsigned short)(r>>16);
}

__device__ __forceinline__ float block_reduce_sum(float v, float* red){
  int t = threadIdx.x;
  red[t]=v; __syncthreads();
  for(int off=128; off>0; off>>=1){ if(t<off) red[t]+=red[t+off]; __syncthreads(); }
  float r = red[0]; __syncthreads();
  return r;
}

// ---------------------------------------------------------------------------
// K0: reordered bf16 weight WcatT[vcol][k] + bias bcat[vcol] (f32).
// R8: also zero-inits am (512 blocks x 256 threads == NPAIR) for k_attn's
// atomicAdd-based head-mean.
__global__ void k_build_w(const float* __restrict__ Wep,
                          const float* __restrict__ bep,
                          const float* __restrict__ Weg,
                          const float* __restrict__ beg,
                          unsigned short* __restrict__ WcatT,
                          float* __restrict__ bcat,
                          float* __restrict__ am){
  int vcol = blockIdx.x, k = threadIdx.x;
  am[(size_t)vcol*256 + k] = 0.f;
  int hv = vcol >> 6, wi = vcol & 63;
  int col = hv*32 + (wi & 31);
  const float* W = (wi < 32) ? Wep : Weg;
  WcatT[(size_t)vcol*256 + k] = f2bf(W[(size_t)k*256 + col]);
  if (k==0){
    const float* bb = (wi<32) ? bep : beg;
    bcat[vcol] = bb[col];
  }
}

// ---------------------------------------------------------------------------
// K1: fused h = node@Wn+bn ; Q,K,V = h@{Wq,Wk,Wv}+bias.  One block per row.
__global__ __launch_bounds__(256) void k_nodeqkv(
    const float* __restrict__ node, const float* __restrict__ Wn,
    const float* __restrict__ bn,
    const float* __restrict__ Wq, const float* __restrict__ bq,
    const float* __restrict__ Wk, const float* __restrict__ bk,
    const float* __restrict__ Wv, const float* __restrict__ bv,
    float* __restrict__ h,
    float* __restrict__ Q, float* __restrict__ K, float* __restrict__ V){
  __shared__ float xs[128];
  __shared__ float hs[256];
  int row = blockIdx.x, c = threadIdx.x;
  if (c < 128) xs[c] = node[(size_t)row*128 + c];
  __syncthreads();
  float acc = bn[c];
#pragma unroll 16
  for (int k=0;k<128;k++) acc += xs[k]*Wn[(size_t)k*256+c];
  h[(size_t)row*256+c] = acc;
  hs[c] = acc;
  __syncthreads();
  float aq = bq[c], ak = bk[c], av = bv[c];
#pragma unroll 16
  for (int k=0;k<256;k++){
    float x = hs[k];
    aq += x*Wq[(size_t)k*256+c];
    ak += x*Wk[(size_t)k*256+c];
    av += x*Wv[(size_t)k*256+c];
  }
  Q[(size_t)row*256+c]=aq; K[(size_t)row*256+c]=ak; V[(size_t)row*256+c]=av;
}

// ---------------------------------------------------------------------------
// KB: big GEMM. C[131072,512] = edge_f32[131072,256] @ WcatT^T (bf16 MFMA).
// R8: 8-wave 256x128 tile. The verified R6 inner loop (2-barrier, fused cvt,
// 88.5µs, no spill) is kept EXACTLY; only the block does 2x rows so
// 2 blocks/CU x 8 waves = 16 waves/CU (vs measured 9.6) and per-block
// prologue/epilogue amortize 2x. kc/ks order unchanged -> bitwise-identical.
// (R6 reg-prefetch and R7 dbuf both spilled: WRITE 52MB/82MB — abandoned.)
__global__ __launch_bounds__(512) void k_edge_gemm(
    const float* __restrict__ edge,            // [NPAIR][256] fp32
    const unsigned short* __restrict__ WcatT,  // [512][256] bf16
    const float* __restrict__ bcat,            // [512]
    float* __restrict__ edge_attn)             // [B*H][N*N]
{
  __shared__ __align__(16) short As[256][72];
  __shared__ __align__(16) short Bs[128][72];
  int id = blockIdx.x;                 // 2048 blocks = 512 bm-tiles x 4 bv
  int bm = ((id>>5)<<3) | (id&7);      // XCD swizzle: bv-siblings share id%8
  int bv = (id>>3)&3;
  int tid = threadIdx.x;
  int w = tid>>6, lane = tid&63;
  int wr = w>>1, wc = w&1;             // wr 0..3 (64-row slice), wc 0..1
  int q = lane>>4, cl = lane&15;

  f32x4 acc[4][4];
#pragma unroll
  for(int i=0;i<4;i++)
#pragma unroll
    for(int j=0;j<4;j++) acc[i][j] = (f32x4){0.f,0.f,0.f,0.f};

  int r0 = tid>>4, c4 = tid&15;        // A staging: 32 row-slots x 16 col-groups
  for(int kc=0;kc<4;kc++){
    int k0 = kc*64;
#pragma unroll
    for(int i=0;i<8;i++){
      int r = r0 + i*32;
      float4 f = *(const float4*)(edge + (size_t)(bm*256+r)*256 + k0 + c4*4);
      __hip_bfloat162 lo = __float22bfloat162_rn(make_float2(f.x,f.y));
      __hip_bfloat162 hi = __float22bfloat162_rn(make_float2(f.z,f.w));
      uint2 u; u.x = *(unsigned int*)&lo; u.y = *(unsigned int*)&hi;
      *(uint2*)(&As[r][c4*4]) = u;
    }
#pragma unroll
    for(int i=0;i<2;i++){
      int g = tid + i*512; int r = g>>3, s8 = g&7;
      *(uint4*)(&Bs[r][s8*8]) = *(const uint4*)(WcatT + (size_t)(bv*128+r)*256 + k0 + s8*8);
    }
    __syncthreads();
#pragma unroll
    for(int ks=0;ks<2;ks++){
      int kb = ks*32 + q*8;
      bf16x8 a[4], bfr[4];
#pragma unroll
      for(int tm=0;tm<4;tm++) a[tm]  = *(const bf16x8*)(&As[wr*64+tm*16+cl][kb]);
#pragma unroll
      for(int tn=0;tn<4;tn++) bfr[tn]= *(const bf16x8*)(&Bs[wc*64+tn*16+cl][kb]);
#pragma unroll
      for(int tm=0;tm<4;tm++)
#pragma unroll
        for(int tn=0;tn<4;tn++)
          acc[tm][tn] = __builtin_amdgcn_mfma_f32_16x16x32_bf16(a[tm], bfr[tn], acc[tm][tn], 0, 0, 0);
    }
    __syncthreads();
  }

  // epilogue: gated reduce over head_dim. tn 0,1 = eh cols, tn 2,3 = eg cols.
  int head = bv*2 + wc;
  float bias[4];
#pragma unroll
  for(int tn=0;tn<4;tn++) bias[tn] = bcat[bv*128 + wc*64 + tn*16 + cl];

#pragma unroll
  for(int tm=0;tm<4;tm++){
    float s[4] = {0.f,0.f,0.f,0.f};
#pragma unroll
    for(int tn=0;tn<2;tn++){
#pragma unroll
      for(int r=0;r<4;r++){
        float eh = acc[tm][tn][r]   + bias[tn];
        float gg = acc[tm][tn+2][r] + bias[tn+2];
        s[r] += eh * (1.f/(1.f + __expf(-gg)));
      }
    }
#pragma unroll
    for(int off=1;off<16;off<<=1){
#pragma unroll
      for(int r=0;r<4;r++) s[r] += __shfl_xor(s[r], off);
    }
    if (cl==0){
      int R = bm*256 + wr*64 + tm*16 + q*4;
      int b = R>>16, rem = R&65535;
#pragma unroll
      for(int r=0;r<4;r++)
        edge_attn[(size_t)(b*NH+head)*65536 + rem + r] = s[r];
    }
  }
}

// ---------------------------------------------------------------------------
// KC: barrier-light attention. Block = (b, hh, 4 query rows); one wave per row.
// R8: head-mean fused via atomicAdd into am (replaces k_attn_mean dispatch).
__global__ __launch_bounds__(256) void k_attn(
    const float* __restrict__ Q, const float* __restrict__ Km,
    const float* __restrict__ V, const int* __restrict__ adj,
    float* __restrict__ attn, float* __restrict__ attn_out,
    float* __restrict__ am){
  __shared__ float Ks[256][33];
  __shared__ float Vs[256][33];
  __shared__ float arow[4][264];
  int b = blockIdx.z, hh = blockIdx.y;
  int t = threadIdx.x;
  int mrow = t>>3, dg = (t&7)*4;
#pragma unroll
  for(int it=0; it<8; it++){
    int m = mrow + it*32;
    size_t base = ((size_t)(b*NN+m))*HID + hh*HD + dg;
    *(float4*)&Ks[m][dg] = *(const float4*)(Km + base);
    *(float4*)&Vs[m][dg] = *(const float4*)(V + base);
  }
  __syncthreads();

  int w = t>>6, lane = t&63;
  int n = blockIdx.x*4 + w;
  const float* qp = Q + ((size_t)(b*NN+n))*HID + hh*HD;
  float4 q[8];
#pragma unroll
  for(int i=0;i<8;i++) q[i] = *(const float4*)(qp + i*4);

  size_t eoff = ((size_t)((b*NH+hh)*NN + n))*NN;
  const int* abase = adj + ((size_t)(b*NN+n))*NN;
  float sc[4];
#pragma unroll
  for(int j=0;j<4;j++){
    int m = lane + j*64;
    float d = 0.f;
#pragma unroll
    for(int i=0;i<8;i++){
      float4 kk = *(float4*)&Ks[m][i*4];
      d += q[i].x*kk.x + q[i].y*kk.y + q[i].z*kk.z + q[i].w*kk.w;
    }
    float s = d*0.17677669529663687f + attn[eoff + m];
    if (abase[m]==0) s = -1e9f;
    sc[j] = s;
  }
  float mx = fmaxf(fmaxf(sc[0],sc[1]),fmaxf(sc[2],sc[3]));
#pragma unroll
  for(int off=1;off<64;off<<=1) mx = fmaxf(mx, __shfl_xor(mx, off));
  float e[4], sum = 0.f;
#pragma unroll
  for(int j=0;j<4;j++){ e[j] = __expf(sc[j]-mx); sum += e[j]; }
#pragma unroll
  for(int off=1;off<64;off<<=1) sum += __shfl_xor(sum, off);
  float inv = 1.f/sum;
  float* amrow = am + (size_t)b*65536 + n*256;
#pragma unroll
  for(int j=0;j<4;j++){
    int m = lane + j*64;
    float a = e[j]*inv;
    attn[eoff + m] = a;
    arow[w][m + (m>>5)] = a;   // stride-33 chunks: AV broadcast reads conflict-free
    atomicAdd(amrow + m, a*0.125f);
  }
  // AV: lane = mc*32-chunk x 4-d-group. o[dg4..dg4+3] = sum_m a[m]*V[m][dg4..]
  int mc = lane>>3, dg4 = (lane&7)*4;
  float4 o = {0.f,0.f,0.f,0.f};
#pragma unroll
  for(int j=0;j<32;j++){
    int m = mc*32 + j;
    float a = arow[w][m + (m>>5)];
    float4 v = *(float4*)&Vs[m][dg4];
    o.x += a*v.x; o.y += a*v.y; o.z += a*v.z; o.w += a*v.w;
  }
#pragma unroll
  for(int off=8; off<64; off<<=1){
    o.x += __shfl_xor(o.x, off); o.y += __shfl_xor(o.y, off);
    o.z += __shfl_xor(o.z, off); o.w += __shfl_xor(o.w, off);
  }
  if (mc==0)
    *(float4*)(attn_out + ((size_t)(b*NN+n))*HID + hh*HD + dg4) = o;
}

// ---------------------------------------------------------------------------
// KD: fused h_out = LN(h + attn_out@Wo + bo) -> d_out ; P = h_out@Weo
__global__ __launch_bounds__(256) void k_hout(
    const float* __restrict__ attn_out, const float* __restrict__ hres,
    const float* __restrict__ Wo, const float* __restrict__ bo,
    const float* __restrict__ g1, const float* __restrict__ b1,
    const float* __restrict__ Weo,
    float* __restrict__ P, float* __restrict__ out){
  __shared__ float xs[256]; __shared__ float red[256]; __shared__ float hs[256];
  int row = blockIdx.x, c = threadIdx.x;
  xs[c] = attn_out[(size_t)row*256 + c];
  __syncthreads();
  float acc = bo[c];
#pragma unroll 16
  for(int k=0;k<256;k++) acc += xs[k]*Wo[(size_t)k*256+c];
  float val = hres[(size_t)row*256+c] + acc;
  float mean = block_reduce_sum(val, red) * (1.f/256.f);
  float ctr = val - mean;
  float var = block_reduce_sum(ctr*ctr, red) * (1.f/256.f);
  float o = ctr * rsqrtf(var + 1e-5f) * g1[c] + b1[c];
  out[(size_t)row*256+c] = o;
  hs[c] = o;
  __syncthreads();
  float accP = 0.f;
#pragma unroll 16
  for(int k=0;k<256;k++) accP += hs[k]*Weo[(size_t)k*256+c];
  P[(size_t)row*256+c] = accP;
}

// ---------------------------------------------------------------------------
// KE: edge_out = LN(edge + attn_mean*0.5*(P[n]+P[m]) + beo). One wave per pair.
__global__ __launch_bounds__(256) void k_edge_out(
    const float* __restrict__ ef, const float* __restrict__ am,
    const float* __restrict__ P, const float* __restrict__ beo,
    const float* __restrict__ g2, const float* __restrict__ b2,
    float* __restrict__ out){
  int w = threadIdx.x>>6, lane = threadIdx.x&63;
  size_t pair = (size_t)blockIdx.x*4 + w;
  int b = (int)(pair>>16); int rem = (int)(pair&65535);
  int n = rem>>8, m = rem&255;
  float a = am[pair]*0.5f;
  const float* Pn = P + (size_t)(b*NN+n)*HID;
  const float* Pm = P + (size_t)(b*NN+m)*HID;
  int c0 = lane*4;
  float4 ev = *(const float4*)(ef + pair*256 + c0);
  float4 pn = *(const float4*)(Pn + c0);
  float4 pm = *(const float4*)(Pm + c0);
  float4 bo4 = *(const float4*)(beo + c0);
  float v0 = ev.x + a*(pn.x+pm.x) + bo4.x;
  float v1 = ev.y + a*(pn.y+pm.y) + bo4.y;
  float v2 = ev.z + a*(pn.z+pm.z) + bo4.z;
  float v3 = ev.w + a*(pn.w+pm.w) + bo4.w;
  float s = v0+v1+v2+v3;
#pragma unroll
  for(int off=1;off<64;off<<=1) s += __shfl_xor(s, off);
  float mean = s*(1.f/256.f);
  float c0f=v0-mean, c1f=v1-mean, c2f=v2-mean, c3f=v3-mean;
  float sq = c0f*c0f+c1f*c1f+c2f*c2f+c3f*c3f;
#pragma unroll
  for(int off=1;off<64;off<<=1) sq += __shfl_xor(sq, off);
  float rs = rsqrtf(sq*(1.f/256.f) + 1e-5f);
  float4 g = *(const float4*)(g2 + c0);
  float4 bb = *(const float4*)(b2 + c0);
  float4 o;
  o.x = c0f*rs*g.x+bb.x;
  o.y = c1f*rs*g.y+bb.y;
  o.z = c2f*rs*g.z+bb.z;
  o.w = c3f*rs*g.w+bb.w;
  *(float4*)(out + pair*256 + c0) = o;
}

// ---------------------------------------------------------------------------
extern "C" void kernel_launch(void* const* d_in, const int* in_sizes, int n_in,
                              void* d_out, int out_size, void* d_ws, size_t ws_size,
                              hipStream_t stream){
  (void)in_sizes; (void)n_in; (void)out_size; (void)ws_size;
  const float* node = (const float*)d_in[0];
  const float* edge = (const float*)d_in[1];
  const int*   adj  = (const int*)d_in[2];
  const float* Wn  = (const float*)d_in[3];
  const float* bn  = (const float*)d_in[4];
  const float* Wq  = (const float*)d_in[5];
  const float* bq  = (const float*)d_in[6];
  const float* Wk  = (const float*)d_in[7];
  const float* bk  = (const float*)d_in[8];
  const float* Wv  = (const float*)d_in[9];
  const float* bv  = (const float*)d_in[10];
  const float* Wep = (const float*)d_in[11];
  const float* bep = (const float*)d_in[12];
  const float* Weg = (const float*)d_in[13];
  const float* beg = (const float*)d_in[14];
  const float* Wo  = (const float*)d_in[15];
  const float* bo  = (const float*)d_in[16];
  const float* Weo = (const float*)d_in[17];
  const float* beo = (const float*)d_in[18];
  const float* g1  = (const float*)d_in[19];
  const float* b1  = (const float*)d_in[20];
  const float* g2  = (const float*)d_in[21];
  const float* b2  = (const float*)d_in[22];

  unsigned short* WcatT = (unsigned short*)d_ws;               // 512*256 bf16
  float* fws  = (float*)((char*)d_ws + (size_t)512*256*2);
  float* bcat = fws;                 // 512
  float* h    = bcat + 512;          // 131072
  float* Q    = h    + 131072;
  float* K    = Q    + 131072;
  float* V    = K    + 131072;
  float* attn = V    + 131072;       // 1048576 (edge_attn, then attn in place)
  float* am   = attn + 1048576;      // 131072
  float* P    = am   + 131072;       // 131072
  float* aout = P    + 131072;       // 131072

  float* out = (float*)d_out;

  k_build_w  <<<512, 256, 0, stream>>>(Wep, bep, Weg, beg, WcatT, bcat, am);
  k_nodeqkv  <<<512, 256, 0, stream>>>(node, Wn, bn, Wq, bq, Wk, bk, Wv, bv, h, Q, K, V);
  k_edge_gemm<<<2048, 512, 0, stream>>>(edge, WcatT, bcat, attn);
  k_attn     <<<dim3(64,8,2), 256, 0, stream>>>(Q, K, V, adj, attn, aout, am);
  k_hout     <<<512, 256, 0, stream>>>(aout, h, Wo, bo, g1, b1, Weo, P, out);
  k_edge_out <<<32768, 256, 0, stream>>>(edge, am, P, beo, g2, b2, out + (size_t)BB*NN*HID);
}

// Round 10
// 393.094 us; speedup vs baseline: 1.1945x; 1.0775x over previous
//
#include <hip/hip_runtime.h>
#include <hip/hip_bf16.h>

#define BB 2
#define NN 256
#define HID 256
#define NH 8
#define HD 32
#define NPAIR (BB*NN*NN)   // 131072

typedef __attribute__((ext_vector_type(8))) short bf16x8;
typedef __attribute__((ext_vector_type(4))) float f32x4;

__device__ __forceinline__ unsigned short f2bf(float f){
  union{float f; unsigned int i;} v; v.f=f;
  unsigned int r = v.i + 0x7fffu + ((v.i>>16)&1u);
  return (unsigned short)(r>>16);
}

__device__ __forceinline__ float block_reduce_sum(float v, float* red){
  int t = threadIdx.x;
  red[t]=v; __syncthreads();
  for(int off=128; off>0; off>>=1){ if(t<off) red[t]+=red[t+off]; __syncthreads(); }
  float r = red[0]; __syncthreads();
  return r;
}

// ---------------------------------------------------------------------------
// K0: reordered bf16 weight WcatT[vcol][k] + bias bcat[vcol] (f32).
// Also zero-inits am (512 x 256 == NPAIR) for k_attn's atomic head-mean.
__global__ void k_build_w(const float* __restrict__ Wep,
                          const float* __restrict__ bep,
                          const float* __restrict__ Weg,
                          const float* __restrict__ beg,
                          unsigned short* __restrict__ WcatT,
                          float* __restrict__ bcat,
                          float* __restrict__ am){
  int vcol = blockIdx.x, k = threadIdx.x;
  am[(size_t)vcol*256 + k] = 0.f;
  int hv = vcol >> 6, wi = vcol & 63;
  int col = hv*32 + (wi & 31);
  const float* W = (wi < 32) ? Wep : Weg;
  WcatT[(size_t)vcol*256 + k] = f2bf(W[(size_t)k*256 + col]);
  if (k==0){
    const float* bb = (wi<32) ? bep : beg;
    bcat[vcol] = bb[col];
  }
}

// ---------------------------------------------------------------------------
// K1: h = node@Wn+bn ; one of {Q,K,V} = h@W+b per block.
// R10: grid (512 rows x 3 mats) = 1536 blocks (6/CU vs 2/CU before) — the
// three serial GEMV chains were interleaved in one thread at 2 blocks/CU
// (latency-bound). h recomputed per mat (cheap), identical accumulation
// order -> bitwise identical. mat 0 writes h.
__global__ __launch_bounds__(256) void k_nodeqkv(
    const float* __restrict__ node, const float* __restrict__ Wn,
    const float* __restrict__ bn,
    const float* __restrict__ Wq, const float* __restrict__ bq,
    const float* __restrict__ Wk, const float* __restrict__ bk,
    const float* __restrict__ Wv, const float* __restrict__ bv,
    float* __restrict__ h,
    float* __restrict__ Q, float* __restrict__ K, float* __restrict__ V){
  __shared__ float xs[128];
  __shared__ float hs[256];
  int row = blockIdx.x, mat = blockIdx.y, c = threadIdx.x;
  if (c < 128) xs[c] = node[(size_t)row*128 + c];
  __syncthreads();
  float acc = bn[c];
#pragma unroll 16
  for (int k=0;k<128;k++) acc += xs[k]*Wn[(size_t)k*256+c];
  if (mat==0) h[(size_t)row*256+c] = acc;
  hs[c] = acc;
  __syncthreads();
  const float* W  = (mat==0)?Wq:((mat==1)?Wk:Wv);
  const float* bb = (mat==0)?bq:((mat==1)?bk:bv);
  float*       O  = (mat==0)?Q :((mat==1)?K :V );
  float a2 = bb[c];
#pragma unroll 16
  for (int k=0;k<256;k++) a2 += hs[k]*W[(size_t)k*256+c];
  O[(size_t)row*256+c] = a2;
}

// ---------------------------------------------------------------------------
// KB: big GEMM. R6-exact (measured 88.5µs, best of 4 variants: reg-prefetch
// spilled 52MB/160µs, dbuf spilled 82MB/150µs, 8-wave tile convoyed 122µs).
// 128x128 tile, 4 blocks/CU, independent-block de-phasing hides latency.
__global__ __launch_bounds__(256) void k_edge_gemm(
    const float* __restrict__ edge,            // [NPAIR][256] fp32
    const unsigned short* __restrict__ WcatT,  // [512][256] bf16
    const float* __restrict__ bcat,            // [512]
    float* __restrict__ edge_attn)             // [B*H][N*N]
{
  __shared__ __align__(16) short As[128][72];
  __shared__ __align__(16) short Bs[128][72];
  int id = blockIdx.x;
  int bm = ((id>>5)<<3) | (id&7);
  int bv = (id>>3)&3;
  int tid = threadIdx.x;
  int w = tid>>6, lane = tid&63;
  int wr = w>>1, wc = w&1;
  int q = lane>>4, cl = lane&15;

  f32x4 acc[4][4];
#pragma unroll
  for(int i=0;i<4;i++)
#pragma unroll
    for(int j=0;j<4;j++) acc[i][j] = (f32x4){0.f,0.f,0.f,0.f};

  int r0 = tid>>4, c4 = tid&15;
  for(int kc=0;kc<4;kc++){
    int k0 = kc*64;
#pragma unroll
    for(int i=0;i<8;i++){
      int r = r0 + i*16;
      float4 f = *(const float4*)(edge + (size_t)(bm*128+r)*256 + k0 + c4*4);
      __hip_bfloat162 lo = __float22bfloat162_rn(make_float2(f.x,f.y));
      __hip_bfloat162 hi = __float22bfloat162_rn(make_float2(f.z,f.w));
      uint2 u; u.x = *(unsigned int*)&lo; u.y = *(unsigned int*)&hi;
      *(uint2*)(&As[r][c4*4]) = u;
    }
#pragma unroll
    for(int i=0;i<4;i++){
      int g = tid + i*256; int r = g>>3, s8 = g&7;
      *(uint4*)(&Bs[r][s8*8]) = *(const uint4*)(WcatT + (size_t)(bv*128+r)*256 + k0 + s8*8);
    }
    __syncthreads();
#pragma unroll
    for(int ks=0;ks<2;ks++){
      int kb = ks*32 + q*8;
      bf16x8 a[4], bfr[4];
#pragma unroll
      for(int tm=0;tm<4;tm++) a[tm]  = *(const bf16x8*)(&As[wr*64+tm*16+cl][kb]);
#pragma unroll
      for(int tn=0;tn<4;tn++) bfr[tn]= *(const bf16x8*)(&Bs[wc*64+tn*16+cl][kb]);
#pragma unroll
      for(int tm=0;tm<4;tm++)
#pragma unroll
        for(int tn=0;tn<4;tn++)
          acc[tm][tn] = __builtin_amdgcn_mfma_f32_16x16x32_bf16(a[tm], bfr[tn], acc[tm][tn], 0, 0, 0);
    }
    __syncthreads();
  }

  int head = bv*2 + wc;
  float bias[4];
#pragma unroll
  for(int tn=0;tn<4;tn++) bias[tn] = bcat[bv*128 + wc*64 + tn*16 + cl];

#pragma unroll
  for(int tm=0;tm<4;tm++){
    float s[4] = {0.f,0.f,0.f,0.f};
#pragma unroll
    for(int tn=0;tn<2;tn++){
#pragma unroll
      for(int r=0;r<4;r++){
        float eh = acc[tm][tn][r]   + bias[tn];
        float gg = acc[tm][tn+2][r] + bias[tn+2];
        s[r] += eh * (1.f/(1.f + __expf(-gg)));
      }
    }
#pragma unroll
    for(int off=1;off<16;off<<=1){
#pragma unroll
      for(int r=0;r<4;r++) s[r] += __shfl_xor(s[r], off);
    }
    if (cl==0){
      int R = bm*128 + wr*64 + tm*16 + q*4;
      int b = R>>16, rem = R&65535;
#pragma unroll
      for(int r=0;r<4;r++)
        edge_attn[(size_t)(b*NH+head)*65536 + rem + r] = s[r];
    }
  }
}

// ---------------------------------------------------------------------------
// KC: barrier-light attention. Block = (b, hh, 4 query rows); one wave per row.
// R10: LDS pad 33 -> 36 floats (144B rows, 16B-aligned). With 33, odd-m rows
// put float4 reads at addr%16==4 -> compiler split each into 4x ds_read_b32
// in BOTH hot loops. 36 restores ds_read_b128; bank stride 36%32=4 -> free
// 2-way. Head-mean fused via atomicAdd (R8, neutral, -1 dispatch).
__global__ __launch_bounds__(256) void k_attn(
    const float* __restrict__ Q, const float* __restrict__ Km,
    const float* __restrict__ V, const int* __restrict__ adj,
    float* __restrict__ attn, float* __restrict__ attn_out,
    float* __restrict__ am){
  __shared__ float Ks[256][36];
  __shared__ float Vs[256][36];
  __shared__ float arow[4][264];
  int b = blockIdx.z, hh = blockIdx.y;
  int t = threadIdx.x;
  int mrow = t>>3, dg = (t&7)*4;
#pragma unroll
  for(int it=0; it<8; it++){
    int m = mrow + it*32;
    size_t base = ((size_t)(b*NN+m))*HID + hh*HD + dg;
    *(float4*)&Ks[m][dg] = *(const float4*)(Km + base);
    *(float4*)&Vs[m][dg] = *(const float4*)(V + base);
  }
  __syncthreads();

  int w = t>>6, lane = t&63;
  int n = blockIdx.x*4 + w;
  const float* qp = Q + ((size_t)(b*NN+n))*HID + hh*HD;
  float4 q[8];
#pragma unroll
  for(int i=0;i<8;i++) q[i] = *(const float4*)(qp + i*4);

  size_t eoff = ((size_t)((b*NH+hh)*NN + n))*NN;
  const int* abase = adj + ((size_t)(b*NN+n))*NN;
  float sc[4];
#pragma unroll
  for(int j=0;j<4;j++){
    int m = lane + j*64;
    float d = 0.f;
#pragma unroll
    for(int i=0;i<8;i++){
      float4 kk = *(float4*)&Ks[m][i*4];
      d += q[i].x*kk.x + q[i].y*kk.y + q[i].z*kk.z + q[i].w*kk.w;
    }
    float s = d*0.17677669529663687f + attn[eoff + m];
    if (abase[m]==0) s = -1e9f;
    sc[j] = s;
  }
  float mx = fmaxf(fmaxf(sc[0],sc[1]),fmaxf(sc[2],sc[3]));
#pragma unroll
  for(int off=1;off<64;off<<=1) mx = fmaxf(mx, __shfl_xor(mx, off));
  float e[4], sum = 0.f;
#pragma unroll
  for(int j=0;j<4;j++){ e[j] = __expf(sc[j]-mx); sum += e[j]; }
#pragma unroll
  for(int off=1;off<64;off<<=1) sum += __shfl_xor(sum, off);
  float inv = 1.f/sum;
  float* amrow = am + (size_t)b*65536 + n*256;
#pragma unroll
  for(int j=0;j<4;j++){
    int m = lane + j*64;
    float a = e[j]*inv;
    attn[eoff + m] = a;
    arow[w][m + (m>>5)] = a;   // stride-33 chunks: AV broadcast reads conflict-free
    atomicAdd(amrow + m, a*0.125f);
  }
  // AV: lane = mc*32-chunk x 4-d-group. o[dg4..dg4+3] = sum_m a[m]*V[m][dg4..]
  int mc = lane>>3, dg4 = (lane&7)*4;
  float4 o = {0.f,0.f,0.f,0.f};
#pragma unroll
  for(int j=0;j<32;j++){
    int m = mc*32 + j;
    float a = arow[w][m + (m>>5)];
    float4 v = *(float4*)&Vs[m][dg4];
    o.x += a*v.x; o.y += a*v.y; o.z += a*v.z; o.w += a*v.w;
  }
#pragma unroll
  for(int off=8; off<64; off<<=1){
    o.x += __shfl_xor(o.x, off); o.y += __shfl_xor(o.y, off);
    o.z += __shfl_xor(o.z, off); o.w += __shfl_xor(o.w, off);
  }
  if (mc==0)
    *(float4*)(attn_out + ((size_t)(b*NN+n))*HID + hh*HD + dg4) = o;
}

// ---------------------------------------------------------------------------
// KD: fused h_out = LN(h + attn_out@Wo + bo) -> d_out ; P = h_out@Weo
__global__ __launch_bounds__(256) void k_hout(
    const float* __restrict__ attn_out, const float* __restrict__ hres,
    const float* __restrict__ Wo, const float* __restrict__ bo,
    const float* __restrict__ g1, const float* __restrict__ b1,
    const float* __restrict__ Weo,
    float* __restrict__ P, float* __restrict__ out){
  __shared__ float xs[256]; __shared__ float red[256]; __shared__ float hs[256];
  int row = blockIdx.x, c = threadIdx.x;
  xs[c] = attn_out[(size_t)row*256 + c];
  __syncthreads();
  float acc = bo[c];
#pragma unroll 16
  for(int k=0;k<256;k++) acc += xs[k]*Wo[(size_t)k*256+c];
  float val = hres[(size_t)row*256+c] + acc;
  float mean = block_reduce_sum(val, red) * (1.f/256.f);
  float ctr = val - mean;
  float var = block_reduce_sum(ctr*ctr, red) * (1.f/256.f);
  float o = ctr * rsqrtf(var + 1e-5f) * g1[c] + b1[c];
  out[(size_t)row*256+c] = o;
  hs[c] = o;
  __syncthreads();
  float accP = 0.f;
#pragma unroll 16
  for(int k=0;k<256;k++) accP += hs[k]*Weo[(size_t)k*256+c];
  P[(size_t)row*256+c] = accP;
}

// ---------------------------------------------------------------------------
// KE: edge_out = LN(edge + attn_mean*0.5*(P[n]+P[m]) + beo). One wave per pair.
__global__ __launch_bounds__(256) void k_edge_out(
    const float* __restrict__ ef, const float* __restrict__ am,
    const float* __restrict__ P, const float* __restrict__ beo,
    const float* __restrict__ g2, const float* __restrict__ b2,
    float* __restrict__ out){
  int w = threadIdx.x>>6, lane = threadIdx.x&63;
  size_t pair = (size_t)blockIdx.x*4 + w;
  int b = (int)(pair>>16); int rem = (int)(pair&65535);
  int n = rem>>8, m = rem&255;
  float a = am[pair]*0.5f;
  const float* Pn = P + (size_t)(b*NN+n)*HID;
  const float* Pm = P + (size_t)(b*NN+m)*HID;
  int c0 = lane*4;
  float4 ev = *(const float4*)(ef + pair*256 + c0);
  float4 pn = *(const float4*)(Pn + c0);
  float4 pm = *(const float4*)(Pm + c0);
  float4 bo4 = *(const float4*)(beo + c0);
  float v0 = ev.x + a*(pn.x+pm.x) + bo4.x;
  float v1 = ev.y + a*(pn.y+pm.y) + bo4.y;
  float v2 = ev.z + a*(pn.z+pm.z) + bo4.z;
  float v3 = ev.w + a*(pn.w+pm.w) + bo4.w;
  float s = v0+v1+v2+v3;
#pragma unroll
  for(int off=1;off<64;off<<=1) s += __shfl_xor(s, off);
  float mean = s*(1.f/256.f);
  float c0f=v0-mean, c1f=v1-mean, c2f=v2-mean, c3f=v3-mean;
  float sq = c0f*c0f+c1f*c1f+c2f*c2f+c3f*c3f;
#pragma unroll
  for(int off=1;off<64;off<<=1) sq += __shfl_xor(sq, off);
  float rs = rsqrtf(sq*(1.f/256.f) + 1e-5f);
  float4 g = *(const float4*)(g2 + c0);
  float4 bb = *(const float4*)(b2 + c0);
  float4 o;
  o.x = c0f*rs*g.x+bb.x;
  o.y = c1f*rs*g.y+bb.y;
  o.z = c2f*rs*g.z+bb.z;
  o.w = c3f*rs*g.w+bb.w;
  *(float4*)(out + pair*256 + c0) = o;
}

// ---------------------------------------------------------------------------
extern "C" void kernel_launch(void* const* d_in, const int* in_sizes, int n_in,
                              void* d_out, int out_size, void* d_ws, size_t ws_size,
                              hipStream_t stream){
  (void)in_sizes; (void)n_in; (void)out_size; (void)ws_size;
  const float* node = (const float*)d_in[0];
  const float* edge = (const float*)d_in[1];
  const int*   adj  = (const int*)d_in[2];
  const float* Wn  = (const float*)d_in[3];
  const float* bn  = (const float*)d_in[4];
  const float* Wq  = (const float*)d_in[5];
  const float* bq  = (const float*)d_in[6];
  const float* Wk  = (const float*)d_in[7];
  const float* bk  = (const float*)d_in[8];
  const float* Wv  = (const float*)d_in[9];
  const float* bv  = (const float*)d_in[10];
  const float* Wep = (const float*)d_in[11];
  const float* bep = (const float*)d_in[12];
  const float* Weg = (const float*)d_in[13];
  const float* beg = (const float*)d_in[14];
  const float* Wo  = (const float*)d_in[15];
  const float* bo  = (const float*)d_in[16];
  const float* Weo = (const float*)d_in[17];
  const float* beo = (const float*)d_in[18];
  const float* g1  = (const float*)d_in[19];
  const float* b1  = (const float*)d_in[20];
  const float* g2  = (const float*)d_in[21];
  const float* b2  = (const float*)d_in[22];

  unsigned short* WcatT = (unsigned short*)d_ws;               // 512*256 bf16
  float* fws  = (float*)((char*)d_ws + (size_t)512*256*2);
  float* bcat = fws;                 // 512
  float* h    = bcat + 512;          // 131072
  float* Q    = h    + 131072;
  float* K    = Q    + 131072;
  float* V    = K    + 131072;
  float* attn = V    + 131072;       // 1048576 (edge_attn, then attn in place)
  float* am   = attn + 1048576;      // 131072
  float* P    = am   + 131072;       // 131072
  float* aout = P    + 131072;       // 131072

  float* out = (float*)d_out;

  k_build_w  <<<512, 256, 0, stream>>>(Wep, bep, Weg, beg, WcatT, bcat, am);
  k_nodeqkv  <<<dim3(512,3), 256, 0, stream>>>(node, Wn, bn, Wq, bq, Wk, bk, Wv, bv, h, Q, K, V);
  k_edge_gemm<<<4096, 256, 0, stream>>>(edge, WcatT, bcat, attn);
  k_attn     <<<dim3(64,8,2), 256, 0, stream>>>(Q, K, V, adj, attn, aout, am);
  k_hout     <<<512, 256, 0, stream>>>(aout, h, Wo, bo, g1, b1, Weo, P, out);
  k_edge_out <<<32768, 256, 0, stream>>>(edge, am, P, beo, g2, b2, out + (size_t)BB*NN*HID);
}

// Round 11
// 388.671 us; speedup vs baseline: 1.2081x; 1.0114x over previous
//
#include <hip/hip_runtime.h>
#include <hip/hip_bf16.h>

#define BB 2
#define NN 256
#define HID 256
#define NH 8
#define HD 32
#define NPAIR (BB*NN*NN)   // 131072

typedef __attribute__((ext_vector_type(8))) short bf16x8;
typedef __attribute__((ext_vector_type(4))) float f32x4;

__device__ __forceinline__ unsigned short f2bf(float f){
  union{float f; unsigned int i;} v; v.f=f;
  unsigned int r = v.i + 0x7fffu + ((v.i>>16)&1u);
  return (unsigned short)(r>>16);
}

__device__ __forceinline__ float block_reduce_sum(float v, float* red){
  int t = threadIdx.x;
  red[t]=v; __syncthreads();
  for(int off=128; off>0; off>>=1){ if(t<off) red[t]+=red[t+off]; __syncthreads(); }
  float r = red[0]; __syncthreads();
  return r;
}

// ---------------------------------------------------------------------------
// K0: reordered bf16 weight WcatT[vcol][k] + bias bcat[vcol] (f32).
// Also zero-inits am (512 x 256 == NPAIR) for k_attn's atomic head-mean.
__global__ void k_build_w(const float* __restrict__ Wep,
                          const float* __restrict__ bep,
                          const float* __restrict__ Weg,
                          const float* __restrict__ beg,
                          unsigned short* __restrict__ WcatT,
                          float* __restrict__ bcat,
                          float* __restrict__ am){
  int vcol = blockIdx.x, k = threadIdx.x;
  am[(size_t)vcol*256 + k] = 0.f;
  int hv = vcol >> 6, wi = vcol & 63;
  int col = hv*32 + (wi & 31);
  const float* W = (wi < 32) ? Wep : Weg;
  WcatT[(size_t)vcol*256 + k] = f2bf(W[(size_t)k*256 + col]);
  if (k==0){
    const float* bb = (wi<32) ? bep : beg;
    bcat[vcol] = bb[col];
  }
}

// ---------------------------------------------------------------------------
// KF: FUSED nodeqkv + edge_gemm (R11). The serial launch chain left the GEMM
// at 29% occupancy with nodeqkv waiting behind it, though they're independent.
// Blocks 0..1535 = nodeqkv (scheduled FIRST so they co-reside with the GEMM's
// first wave-set and fill its barrier stalls); blocks 1536..5631 = the R6-exact
// GEMM (measured 87.6µs, best of 5 structural variants). Both bodies bitwise-
// identical to their standalone versions; branch is block-uniform.
__global__ __launch_bounds__(256) void k_gemm_qkv(
    const float* __restrict__ edge,            // [NPAIR][256] fp32
    const unsigned short* __restrict__ WcatT,  // [512][256] bf16
    const float* __restrict__ bcat,            // [512]
    float* __restrict__ edge_attn,             // [B*H][N*N]
    const float* __restrict__ node, const float* __restrict__ Wn,
    const float* __restrict__ bn,
    const float* __restrict__ Wq, const float* __restrict__ bq,
    const float* __restrict__ Wk, const float* __restrict__ bk,
    const float* __restrict__ Wv, const float* __restrict__ bv,
    float* __restrict__ h,
    float* __restrict__ Q, float* __restrict__ K, float* __restrict__ V)
{
  __shared__ __align__(16) short As[128][72];
  __shared__ __align__(16) short Bs[128][72];
  __shared__ float xs[128];
  __shared__ float hs[256];

  if (blockIdx.x < 1536){
    // ---- nodeqkv body (R10-exact): row x mat, bitwise-identical chains ----
    int row = blockIdx.x & 511, mat = blockIdx.x >> 9, c = threadIdx.x;
    if (c < 128) xs[c] = node[(size_t)row*128 + c];
    __syncthreads();
    float acc = bn[c];
#pragma unroll 16
    for (int k=0;k<128;k++) acc += xs[k]*Wn[(size_t)k*256+c];
    if (mat==0) h[(size_t)row*256+c] = acc;
    hs[c] = acc;
    __syncthreads();
    const float* W  = (mat==0)?Wq:((mat==1)?Wk:Wv);
    const float* bb = (mat==0)?bq:((mat==1)?bk:bv);
    float*       O  = (mat==0)?Q :((mat==1)?K :V );
    float a2 = bb[c];
#pragma unroll 16
    for (int k=0;k<256;k++) a2 += hs[k]*W[(size_t)k*256+c];
    O[(size_t)row*256+c] = a2;
    return;
  }

  // ---- gemm body (R6-exact) ----
  int id = blockIdx.x - 1536;
  int bm = ((id>>5)<<3) | (id&7);
  int bv2 = (id>>3)&3;
  int tid = threadIdx.x;
  int w = tid>>6, lane = tid&63;
  int wr = w>>1, wc = w&1;
  int q = lane>>4, cl = lane&15;

  f32x4 acc[4][4];
#pragma unroll
  for(int i=0;i<4;i++)
#pragma unroll
    for(int j=0;j<4;j++) acc[i][j] = (f32x4){0.f,0.f,0.f,0.f};

  int r0 = tid>>4, c4 = tid&15;
  for(int kc=0;kc<4;kc++){
    int k0 = kc*64;
#pragma unroll
    for(int i=0;i<8;i++){
      int r = r0 + i*16;
      float4 f = *(const float4*)(edge + (size_t)(bm*128+r)*256 + k0 + c4*4);
      __hip_bfloat162 lo = __float22bfloat162_rn(make_float2(f.x,f.y));
      __hip_bfloat162 hi = __float22bfloat162_rn(make_float2(f.z,f.w));
      uint2 u; u.x = *(unsigned int*)&lo; u.y = *(unsigned int*)&hi;
      *(uint2*)(&As[r][c4*4]) = u;
    }
#pragma unroll
    for(int i=0;i<4;i++){
      int g = tid + i*256; int r = g>>3, s8 = g&7;
      *(uint4*)(&Bs[r][s8*8]) = *(const uint4*)(WcatT + (size_t)(bv2*128+r)*256 + k0 + s8*8);
    }
    __syncthreads();
#pragma unroll
    for(int ks=0;ks<2;ks++){
      int kb = ks*32 + q*8;
      bf16x8 a[4], bfr[4];
#pragma unroll
      for(int tm=0;tm<4;tm++) a[tm]  = *(const bf16x8*)(&As[wr*64+tm*16+cl][kb]);
#pragma unroll
      for(int tn=0;tn<4;tn++) bfr[tn]= *(const bf16x8*)(&Bs[wc*64+tn*16+cl][kb]);
#pragma unroll
      for(int tm=0;tm<4;tm++)
#pragma unroll
        for(int tn=0;tn<4;tn++)
          acc[tm][tn] = __builtin_amdgcn_mfma_f32_16x16x32_bf16(a[tm], bfr[tn], acc[tm][tn], 0, 0, 0);
    }
    __syncthreads();
  }

  int head = bv2*2 + wc;
  float bias[4];
#pragma unroll
  for(int tn=0;tn<4;tn++) bias[tn] = bcat[bv2*128 + wc*64 + tn*16 + cl];

#pragma unroll
  for(int tm=0;tm<4;tm++){
    float s[4] = {0.f,0.f,0.f,0.f};
#pragma unroll
    for(int tn=0;tn<2;tn++){
#pragma unroll
      for(int r=0;r<4;r++){
        float eh = acc[tm][tn][r]   + bias[tn];
        float gg = acc[tm][tn+2][r] + bias[tn+2];
        s[r] += eh * (1.f/(1.f + __expf(-gg)));
      }
    }
#pragma unroll
    for(int off=1;off<16;off<<=1){
#pragma unroll
      for(int r=0;r<4;r++) s[r] += __shfl_xor(s[r], off);
    }
    if (cl==0){
      int R = bm*128 + wr*64 + tm*16 + q*4;
      int b = R>>16, rem = R&65535;
#pragma unroll
      for(int r=0;r<4;r++)
        edge_attn[(size_t)(b*NH+head)*65536 + rem + r] = s[r];
    }
  }
}

// ---------------------------------------------------------------------------
// KC: attention. R11: grid (32,8,2) — each block stages K/V ONCE and processes
// 8 query rows (2 reps x 4 waves). Before, 64 blocks per (b,hh) re-staged the
// same 64KB K/V 64x. arow is per-wave -> no barrier needed between reps.
// Head-mean fused via atomicAdd (R8).
__global__ __launch_bounds__(256) void k_attn(
    const float* __restrict__ Q, const float* __restrict__ Km,
    const float* __restrict__ V, const int* __restrict__ adj,
    float* __restrict__ attn, float* __restrict__ attn_out,
    float* __restrict__ am){
  __shared__ float Ks[256][36];
  __shared__ float Vs[256][36];
  __shared__ float arow[4][264];
  int b = blockIdx.z, hh = blockIdx.y;
  int t = threadIdx.x;
  int mrow = t>>3, dg = (t&7)*4;
#pragma unroll
  for(int it=0; it<8; it++){
    int m = mrow + it*32;
    size_t base = ((size_t)(b*NN+m))*HID + hh*HD + dg;
    *(float4*)&Ks[m][dg] = *(const float4*)(Km + base);
    *(float4*)&Vs[m][dg] = *(const float4*)(V + base);
  }
  __syncthreads();

  int w = t>>6, lane = t&63;
  int mc = lane>>3, dg4 = (lane&7)*4;

  for (int rep=0; rep<2; ++rep){
    int n = blockIdx.x*8 + rep*4 + w;
    const float* qp = Q + ((size_t)(b*NN+n))*HID + hh*HD;
    float4 q[8];
#pragma unroll
    for(int i=0;i<8;i++) q[i] = *(const float4*)(qp + i*4);

    size_t eoff = ((size_t)((b*NH+hh)*NN + n))*NN;
    const int* abase = adj + ((size_t)(b*NN+n))*NN;
    float sc[4];
#pragma unroll
    for(int j=0;j<4;j++){
      int m = lane + j*64;
      float d = 0.f;
#pragma unroll
      for(int i=0;i<8;i++){
        float4 kk = *(float4*)&Ks[m][i*4];
        d += q[i].x*kk.x + q[i].y*kk.y + q[i].z*kk.z + q[i].w*kk.w;
      }
      float s = d*0.17677669529663687f + attn[eoff + m];
      if (abase[m]==0) s = -1e9f;
      sc[j] = s;
    }
    float mx = fmaxf(fmaxf(sc[0],sc[1]),fmaxf(sc[2],sc[3]));
#pragma unroll
    for(int off=1;off<64;off<<=1) mx = fmaxf(mx, __shfl_xor(mx, off));
    float e[4], sum = 0.f;
#pragma unroll
    for(int j=0;j<4;j++){ e[j] = __expf(sc[j]-mx); sum += e[j]; }
#pragma unroll
    for(int off=1;off<64;off<<=1) sum += __shfl_xor(sum, off);
    float inv = 1.f/sum;
    float* amrow = am + (size_t)b*65536 + n*256;
#pragma unroll
    for(int j=0;j<4;j++){
      int m = lane + j*64;
      float a = e[j]*inv;
      attn[eoff + m] = a;
      arow[w][m + (m>>5)] = a;   // stride-33 chunks: conflict-free broadcast
      atomicAdd(amrow + m, a*0.125f);
    }
    float4 o = {0.f,0.f,0.f,0.f};
#pragma unroll
    for(int j=0;j<32;j++){
      int m = mc*32 + j;
      float a = arow[w][m + (m>>5)];
      float4 v = *(float4*)&Vs[m][dg4];
      o.x += a*v.x; o.y += a*v.y; o.z += a*v.z; o.w += a*v.w;
    }
#pragma unroll
    for(int off=8; off<64; off<<=1){
      o.x += __shfl_xor(o.x, off); o.y += __shfl_xor(o.y, off);
      o.z += __shfl_xor(o.z, off); o.w += __shfl_xor(o.w, off);
    }
    if (mc==0)
      *(float4*)(attn_out + ((size_t)(b*NN+n))*HID + hh*HD + dg4) = o;
  }
}

// ---------------------------------------------------------------------------
// KD: fused h_out = LN(h + attn_out@Wo + bo) -> d_out ; P = h_out@Weo
__global__ __launch_bounds__(256) void k_hout(
    const float* __restrict__ attn_out, const float* __restrict__ hres,
    const float* __restrict__ Wo, const float* __restrict__ bo,
    const float* __restrict__ g1, const float* __restrict__ b1,
    const float* __restrict__ Weo,
    float* __restrict__ P, float* __restrict__ out){
  __shared__ float xs[256]; __shared__ float red[256]; __shared__ float hs[256];
  int row = blockIdx.x, c = threadIdx.x;
  xs[c] = attn_out[(size_t)row*256 + c];
  __syncthreads();
  float acc = bo[c];
#pragma unroll 16
  for(int k=0;k<256;k++) acc += xs[k]*Wo[(size_t)k*256+c];
  float val = hres[(size_t)row*256+c] + acc;
  float mean = block_reduce_sum(val, red) * (1.f/256.f);
  float ctr = val - mean;
  float var = block_reduce_sum(ctr*ctr, red) * (1.f/256.f);
  float o = ctr * rsqrtf(var + 1e-5f) * g1[c] + b1[c];
  out[(size_t)row*256+c] = o;
  hs[c] = o;
  __syncthreads();
  float accP = 0.f;
#pragma unroll 16
  for(int k=0;k<256;k++) accP += hs[k]*Weo[(size_t)k*256+c];
  P[(size_t)row*256+c] = accP;
}

// ---------------------------------------------------------------------------
// KE: edge_out = LN(edge + attn_mean*0.5*(P[n]+P[m]) + beo). One wave per pair.
__global__ __launch_bounds__(256) void k_edge_out(
    const float* __restrict__ ef, const float* __restrict__ am,
    const float* __restrict__ P, const float* __restrict__ beo,
    const float* __restrict__ g2, const float* __restrict__ b2,
    float* __restrict__ out){
  int w = threadIdx.x>>6, lane = threadIdx.x&63;
  size_t pair = (size_t)blockIdx.x*4 + w;
  int b = (int)(pair>>16); int rem = (int)(pair&65535);
  int n = rem>>8, m = rem&255;
  float a = am[pair]*0.5f;
  const float* Pn = P + (size_t)(b*NN+n)*HID;
  const float* Pm = P + (size_t)(b*NN+m)*HID;
  int c0 = lane*4;
  float4 ev = *(const float4*)(ef + pair*256 + c0);
  float4 pn = *(const float4*)(Pn + c0);
  float4 pm = *(const float4*)(Pm + c0);
  float4 bo4 = *(const float4*)(beo + c0);
  float v0 = ev.x + a*(pn.x+pm.x) + bo4.x;
  float v1 = ev.y + a*(pn.y+pm.y) + bo4.y;
  float v2 = ev.z + a*(pn.z+pm.z) + bo4.z;
  float v3 = ev.w + a*(pn.w+pm.w) + bo4.w;
  float s = v0+v1+v2+v3;
#pragma unroll
  for(int off=1;off<64;off<<=1) s += __shfl_xor(s, off);
  float mean = s*(1.f/256.f);
  float c0f=v0-mean, c1f=v1-mean, c2f=v2-mean, c3f=v3-mean;
  float sq = c0f*c0f+c1f*c1f+c2f*c2f+c3f*c3f;
#pragma unroll
  for(int off=1;off<64;off<<=1) sq += __shfl_xor(sq, off);
  float rs = rsqrtf(sq*(1.f/256.f) + 1e-5f);
  float4 g = *(const float4*)(g2 + c0);
  float4 bb = *(const float4*)(b2 + c0);
  float4 o;
  o.x = c0f*rs*g.x+bb.x;
  o.y = c1f*rs*g.y+bb.y;
  o.z = c2f*rs*g.z+bb.z;
  o.w = c3f*rs*g.w+bb.w;
  *(float4*)(out + pair*256 + c0) = o;
}

// ---------------------------------------------------------------------------
extern "C" void kernel_launch(void* const* d_in, const int* in_sizes, int n_in,
                              void* d_out, int out_size, void* d_ws, size_t ws_size,
                              hipStream_t stream){
  (void)in_sizes; (void)n_in; (void)out_size; (void)ws_size;
  const float* node = (const float*)d_in[0];
  const float* edge = (const float*)d_in[1];
  const int*   adj  = (const int*)d_in[2];
  const float* Wn  = (const float*)d_in[3];
  const float* bn  = (const float*)d_in[4];
  const float* Wq  = (const float*)d_in[5];
  const float* bq  = (const float*)d_in[6];
  const float* Wk  = (const float*)d_in[7];
  const float* bk  = (const float*)d_in[8];
  const float* Wv  = (const float*)d_in[9];
  const float* bv  = (const float*)d_in[10];
  const float* Wep = (const float*)d_in[11];
  const float* bep = (const float*)d_in[12];
  const float* Weg = (const float*)d_in[13];
  const float* beg = (const float*)d_in[14];
  const float* Wo  = (const float*)d_in[15];
  const float* bo  = (const float*)d_in[16];
  const float* Weo = (const float*)d_in[17];
  const float* beo = (const float*)d_in[18];
  const float* g1  = (const float*)d_in[19];
  const float* b1  = (const float*)d_in[20];
  const float* g2  = (const float*)d_in[21];
  const float* b2  = (const float*)d_in[22];

  unsigned short* WcatT = (unsigned short*)d_ws;               // 512*256 bf16
  float* fws  = (float*)((char*)d_ws + (size_t)512*256*2);
  float* bcat = fws;                 // 512
  float* h    = bcat + 512;          // 131072
  float* Q    = h    + 131072;
  float* K    = Q    + 131072;
  float* V    = K    + 131072;
  float* attn = V    + 131072;       // 1048576 (edge_attn, then attn in place)
  float* am   = attn + 1048576;      // 131072
  float* P    = am   + 131072;       // 131072
  float* aout = P    + 131072;       // 131072

  float* out = (float*)d_out;

  k_build_w  <<<512, 256, 0, stream>>>(Wep, bep, Weg, beg, WcatT, bcat, am);
  k_gemm_qkv <<<5632, 256, 0, stream>>>(edge, WcatT, bcat, attn,
                                        node, Wn, bn, Wq, bq, Wk, bk, Wv, bv, h, Q, K, V);
  k_attn     <<<dim3(32,8,2), 256, 0, stream>>>(Q, K, V, adj, attn, aout, am);
  k_hout     <<<512, 256, 0, stream>>>(aout, h, Wo, bo, g1, b1, Weo, P, out);
  k_edge_out <<<32768, 256, 0, stream>>>(edge, am, P, beo, g2, b2, out + (size_t)BB*NN*HID);
}